// Round 4
// baseline (452.191 us; speedup 1.0000x reference)
//
#include <hip/hip_runtime.h>

typedef __attribute__((ext_vector_type(8))) __bf16 bf16x8;
typedef __attribute__((ext_vector_type(4))) float f32x4;

#define NB   4
#define NS   2048
#define NDIN 1024
#define NH   16
#define ND   64
#define NHD  1024
#define NM   (NB * NS)  // 8192

__device__ __forceinline__ float bf2f(unsigned short u) {
    unsigned int x = ((unsigned int)u) << 16;
    return __builtin_bit_cast(float, x);
}
__device__ __forceinline__ unsigned short f2bf(float f) {
    unsigned int u = __builtin_bit_cast(unsigned int, f);
    u += 0x7fff + ((u >> 16) & 1);  // RNE
    return (unsigned short)(u >> 16);
}
__device__ __forceinline__ unsigned int pack2bf(float a, float b) {
    return (unsigned int)f2bf(a) | ((unsigned int)f2bf(b) << 16);
}

// ---------------- X: fp32 -> bf16, 8 elems/thread ----------------
__global__ __launch_bounds__(256) void cvt_x(const float* __restrict__ src,
                                             unsigned short* __restrict__ dst) {
    int i = blockIdx.x * 256 + threadIdx.x;
    float4 a = ((const float4*)src)[i * 2];
    float4 b = ((const float4*)src)[i * 2 + 1];
    union { uint4 u; unsigned short s[8]; } o;
    o.s[0] = f2bf(a.x); o.s[1] = f2bf(a.y); o.s[2] = f2bf(a.z); o.s[3] = f2bf(a.w);
    o.s[4] = f2bf(b.x); o.s[5] = f2bf(b.y); o.s[6] = f2bf(b.z); o.s[7] = f2bf(b.w);
    *(uint4*)(dst + (size_t)i * 8) = o.u;
}

// ------------- weight transpose+convert: fp32 src[K][N] -> bf16 dst[N][K] -------------
__global__ void transpose_cvt(const float* __restrict__ src,
                              unsigned short* __restrict__ dst, int K, int N) {
    __shared__ unsigned short t[32][33];
    int k0 = blockIdx.x * 32, n0 = blockIdx.y * 32;
    int tx = threadIdx.x, ty = threadIdx.y;  // block (32,8)
#pragma unroll
    for (int i = 0; i < 32; i += 8)
        t[ty + i][tx] = f2bf(src[(size_t)(k0 + ty + i) * N + (n0 + tx)]);
    __syncthreads();
#pragma unroll
    for (int i = 0; i < 32; i += 8)
        dst[(size_t)(n0 + ty + i) * K + (k0 + tx)] = t[tx][ty + i];
}

// ---------------- fused QKV projection: Xb[8192][1024] @ {wq,wk,wv} ----------------
// Q,K scattered as [B,H,S,D]; V scattered TRANSPOSED as VT[B,H,D,S].
__global__ __launch_bounds__(256) void gemm_qkv(
    const unsigned short* __restrict__ X, const unsigned short* __restrict__ Wt,
    const float* __restrict__ bq, const float* __restrict__ bk,
    const float* __restrict__ bv,
    unsigned short* __restrict__ Q, unsigned short* __restrict__ K,
    unsigned short* __restrict__ VT) {
    __shared__ unsigned short Al[128][40];
    __shared__ unsigned short Bl[128][40];
    int mb = blockIdx.x * 128;
    int nb = blockIdx.y * 128;
    int tid = threadIdx.x;
    int wid = tid >> 6, lane = tid & 63, quad = lane >> 4, l16 = lane & 15;
    int wm = (wid & 1) * 64, wn = (wid >> 1) * 64;

    f32x4 acc[4][4];
#pragma unroll
    for (int i = 0; i < 4; i++)
#pragma unroll
        for (int j = 0; j < 4; j++) acc[i][j] = (f32x4){0.f, 0.f, 0.f, 0.f};

    for (int k0 = 0; k0 < NDIN; k0 += 32) {
#pragma unroll
        for (int i = 0; i < 2; i++) {
            int c = tid + 256 * i;
            int row = c >> 2, col = (c & 3) * 8;
            uint4 a = *(const uint4*)(X + (size_t)(mb + row) * NDIN + k0 + col);
            *(uint4*)(&Al[row][col]) = a;
            uint4 b = *(const uint4*)(Wt + (size_t)(nb + row) * NDIN + k0 + col);
            *(uint4*)(&Bl[row][col]) = b;
        }
        __syncthreads();
        bf16x8 af[4], bfr[4];
#pragma unroll
        for (int i = 0; i < 4; i++)
            af[i] = *(const bf16x8*)(&Al[wm + i * 16 + l16][quad * 8]);
#pragma unroll
        for (int j = 0; j < 4; j++)
            bfr[j] = *(const bf16x8*)(&Bl[wn + j * 16 + l16][quad * 8]);
#pragma unroll
        for (int i = 0; i < 4; i++)
#pragma unroll
            for (int j = 0; j < 4; j++)
                acc[i][j] = __builtin_amdgcn_mfma_f32_16x16x32_bf16(af[i], bfr[j], acc[i][j], 0, 0, 0);
        __syncthreads();
    }

#pragma unroll
    for (int i = 0; i < 4; i++) {
#pragma unroll
        for (int j = 0; j < 4; j++) {
            int n = nb + wn + j * 16 + l16;
            int wsel = n >> 10;
            int cc = n & 1023;
            const float* bias = (wsel == 0) ? bq : (wsel == 1) ? bk : bv;
            float bias_v = bias[cc];
            int h = cc >> 6, d = cc & 63;
#pragma unroll
            for (int r = 0; r < 4; r++) {
                int m = mb + wm + i * 16 + quad * 4 + r;
                int b = m >> 11, s = m & 2047;
                unsigned short val = f2bf(acc[i][j][r] + bias_v);
                if (wsel == 0)
                    Q[((size_t)((b * NH + h) * NS + s)) * ND + d] = val;
                else if (wsel == 1)
                    K[((size_t)((b * NH + h) * NS + s)) * ND + d] = val;
                else
                    VT[((size_t)((b * NH + h) * ND + d)) * NS + s] = val;
            }
        }
    }
}

// ---------------- barrier-free transposed flash attention ----------------
// S^T = K Q^T (A=K, B=Q); O^T = V^T P^T (A=V^T, B=P^T). Lane l16 owns q-column.
// Pl is wave-private: ds ordering via s_waitcnt only, NO __syncthreads anywhere.
__global__ __launch_bounds__(256, 4) void attn(
    const unsigned short* __restrict__ Q, const unsigned short* __restrict__ K,
    const unsigned short* __restrict__ VT, unsigned short* __restrict__ Obuf) {
    __shared__ unsigned short Pl[4][32][72];  // per-wave P^T scratch [q][key]
    int qt = blockIdx.x;  // 0..15
    int bh = blockIdx.y;  // 0..63
    size_t kbase = (size_t)bh * NS * ND;  // K : [bh][s][d]
    size_t vbase = (size_t)bh * ND * NS;  // VT: [bh][d][s]
    int tid = threadIdx.x, wid = tid >> 6, lane = tid & 63;
    int quad = lane >> 4, l16 = lane & 15;
    int q0 = qt * 128 + wid * 32;
    const float L2E = 1.44269504f;

    // Q as B-operand fragments (lane=q-row, k=d), pre-scaled by 1/8 (exact in bf16)
    bf16x8 qa[2][2];
#pragma unroll
    for (int s = 0; s < 2; s++)
#pragma unroll
        for (int h = 0; h < 2; h++) {
            union { uint4 u; unsigned short sv[8]; } in_, out_;
            in_.u = *(const uint4*)(Q + kbase + (size_t)(q0 + s * 16 + l16) * ND + h * 32 + quad * 8);
#pragma unroll
            for (int j = 0; j < 8; j++) out_.sv[j] = f2bf(bf2f(in_.sv[j]) * 0.125f);
            qa[s][h] = __builtin_bit_cast(bf16x8, out_.u);
        }

    bf16x8 ones;
    {
        union { uint4 u; unsigned short sv[8]; } t;
#pragma unroll
        for (int j = 0; j < 8; j++) t.sv[j] = 0x3F80;  // bf16 1.0
        ones = __builtin_bit_cast(bf16x8, t.u);
    }

    float mrow[2] = {-1e30f, -1e30f};
    f32x4 lacc[2];
    f32x4 o[2][4];
#pragma unroll
    for (int s = 0; s < 2; s++) lacc[s] = (f32x4){0.f, 0.f, 0.f, 0.f};
#pragma unroll
    for (int s = 0; s < 2; s++)
#pragma unroll
        for (int t = 0; t < 4; t++) o[s][t] = (f32x4){0.f, 0.f, 0.f, 0.f};

    for (int kc = 0; kc < NS; kc += 64) {
        // K A-fragments straight from global (L1-hot: 8KB/chunk shared by 4 waves)
        bf16x8 kb[4][2];
#pragma unroll
        for (int sub = 0; sub < 4; sub++)
#pragma unroll
            for (int h = 0; h < 2; h++)
                kb[sub][h] = *(const bf16x8*)(K + kbase + (size_t)(kc + sub * 16 + l16) * ND + h * 32 + quad * 8);

        // S^T tiles: C[m=key][n=q]
        f32x4 sc[2][4];
#pragma unroll
        for (int sub = 0; sub < 4; sub++)
#pragma unroll
            for (int s = 0; s < 2; s++) {
                f32x4 c = (f32x4){0.f, 0.f, 0.f, 0.f};
                c = __builtin_amdgcn_mfma_f32_16x16x32_bf16(kb[sub][0], qa[s][0], c, 0, 0, 0);
                c = __builtin_amdgcn_mfma_f32_16x16x32_bf16(kb[sub][1], qa[s][1], c, 0, 0, 0);
                sc[s][sub] = c;
            }

        // online softmax: lane owns q-column l16 -> one (m,l) per s
#pragma unroll
        for (int s = 0; s < 2; s++) {
            float mx = sc[s][0][0];
#pragma unroll
            for (int sub = 0; sub < 4; sub++)
#pragma unroll
                for (int r = 0; r < 4; r++) mx = fmaxf(mx, sc[s][sub][r]);
            mx = fmaxf(mx, __shfl_xor(mx, 16, 64));
            mx = fmaxf(mx, __shfl_xor(mx, 32, 64));
            float mn = fmaxf(mrow[s], mx);
            float alpha = __builtin_exp2f((mrow[s] - mn) * L2E);
            mrow[s] = mn;
            float mc = mn * L2E;
#pragma unroll
            for (int t = 0; t < 4; t++) o[s][t] *= alpha;
            lacc[s] *= alpha;
            // exp, pack pairs, b64 store into wave-private Pl (P^T[q][key])
#pragma unroll
            for (int sub = 0; sub < 4; sub++) {
                float p0 = __builtin_exp2f(fmaf(sc[s][sub][0], L2E, -mc));
                float p1 = __builtin_exp2f(fmaf(sc[s][sub][1], L2E, -mc));
                float p2 = __builtin_exp2f(fmaf(sc[s][sub][2], L2E, -mc));
                float p3 = __builtin_exp2f(fmaf(sc[s][sub][3], L2E, -mc));
                uint2 pk;
                pk.x = pack2bf(p0, p1);
                pk.y = pack2bf(p2, p3);
                *(uint2*)(&Pl[wid][s * 16 + l16][sub * 16 + quad * 4]) = pk;
            }
        }

        // V^T A-fragments (issue while Pl stores drain)
        bf16x8 vb[4][2];
#pragma unroll
        for (int t = 0; t < 4; t++)
#pragma unroll
            for (int h = 0; h < 2; h++)
                vb[t][h] = *(const bf16x8*)(VT + vbase + (size_t)(t * 16 + l16) * NS + kc + h * 32 + quad * 8);

        // wave-local write->read ordering (Pl is per-wid; no barrier needed)
        asm volatile("s_waitcnt lgkmcnt(0)" ::: "memory");

#pragma unroll
        for (int s = 0; s < 2; s++) {
            bf16x8 pb0 = *(const bf16x8*)(&Pl[wid][s * 16 + l16][quad * 8]);
            bf16x8 pb1 = *(const bf16x8*)(&Pl[wid][s * 16 + l16][32 + quad * 8]);
#pragma unroll
            for (int t = 0; t < 4; t++) {
                o[s][t] = __builtin_amdgcn_mfma_f32_16x16x32_bf16(vb[t][0], pb0, o[s][t], 0, 0, 0);
                o[s][t] = __builtin_amdgcn_mfma_f32_16x16x32_bf16(vb[t][1], pb1, o[s][t], 0, 0, 0);
            }
            lacc[s] = __builtin_amdgcn_mfma_f32_16x16x32_bf16(ones, pb0, lacc[s], 0, 0, 0);
            lacc[s] = __builtin_amdgcn_mfma_f32_16x16x32_bf16(ones, pb1, lacc[s], 0, 0, 0);
        }
    }

    // epilogue: O^T C-layout -> Obuf[m][h*64+d], packed pair stores
    int b = bh >> 4, h = bh & 15;
#pragma unroll
    for (int s = 0; s < 2; s++) {
        float rl = 1.0f / lacc[s][0];
        size_t row = (size_t)(b * NS + q0 + s * 16 + l16) * NHD + h * ND;
#pragma unroll
        for (int t = 0; t < 4; t++) {
            int d = t * 16 + quad * 4;
            *(unsigned int*)(&Obuf[row + d])     = pack2bf(o[s][t][0] * rl, o[s][t][1] * rl);
            *(unsigned int*)(&Obuf[row + d + 2]) = pack2bf(o[s][t][2] * rl, o[s][t][3] * rl);
        }
    }
}

// ---------------- output projection: Obuf[8192][1024] @ wo[1024][64] + bo -> fp32 ----------------
__global__ __launch_bounds__(64) void out_proj(
    const unsigned short* __restrict__ Obuf, const unsigned short* __restrict__ WoT,
    const float* __restrict__ bo, float* __restrict__ Out) {
    int m0 = blockIdx.x * 16;
    int lane = threadIdx.x, quad = lane >> 4, l16 = lane & 15;
    f32x4 acc[4];
#pragma unroll
    for (int t = 0; t < 4; t++) acc[t] = (f32x4){0.f, 0.f, 0.f, 0.f};
    for (int k0 = 0; k0 < NHD; k0 += 32) {
        bf16x8 a = *(const bf16x8*)(Obuf + (size_t)(m0 + l16) * NHD + k0 + quad * 8);
#pragma unroll
        for (int t = 0; t < 4; t++) {
            bf16x8 b = *(const bf16x8*)(WoT + (size_t)(t * 16 + l16) * NHD + k0 + quad * 8);
            acc[t] = __builtin_amdgcn_mfma_f32_16x16x32_bf16(a, b, acc[t], 0, 0, 0);
        }
    }
#pragma unroll
    for (int t = 0; t < 4; t++) {
        int n = t * 16 + l16;
        float bb = bo[n];
#pragma unroll
        for (int r = 0; r < 4; r++) {
            int m = m0 + quad * 4 + r;
            Out[(size_t)m * ND + n] = acc[t][r] + bb;
        }
    }
}

extern "C" void kernel_launch(void* const* d_in, const int* in_sizes, int n_in,
                              void* d_out, int out_size, void* d_ws, size_t ws_size,
                              hipStream_t stream) {
    const float* X  = (const float*)d_in[0];
    const float* wq = (const float*)d_in[1];
    const float* bq = (const float*)d_in[2];
    const float* wk = (const float*)d_in[3];
    const float* bk = (const float*)d_in[4];
    const float* wv = (const float*)d_in[5];
    const float* bv = (const float*)d_in[6];
    const float* wo = (const float*)d_in[7];
    const float* bo = (const float*)d_in[8];
    float* Out = (float*)d_out;

    char* w = (char*)d_ws;
    unsigned short* Wt  = (unsigned short*)w; w += (size_t)3072 * 1024 * 2;
    unsigned short* WoT = (unsigned short*)w; w += (size_t)64 * 1024 * 2;
    unsigned short* Xb  = (unsigned short*)w; w += (size_t)NM * NDIN * 2;
    unsigned short* Qb  = (unsigned short*)w; w += (size_t)NM * NHD * 2;
    unsigned short* Kb  = (unsigned short*)w; w += (size_t)NM * NHD * 2;
    unsigned short* VTb = (unsigned short*)w; w += (size_t)NM * NHD * 2;
    unsigned short* Ob  = (unsigned short*)w; w += (size_t)NM * NHD * 2;

    cvt_x<<<NM * NDIN / (256 * 8), 256, 0, stream>>>(X, Xb);

    dim3 tb(32, 8);
    transpose_cvt<<<dim3(32, 32), tb, 0, stream>>>(wq, Wt, 1024, 1024);
    transpose_cvt<<<dim3(32, 32), tb, 0, stream>>>(wk, Wt + 1024 * 1024, 1024, 1024);
    transpose_cvt<<<dim3(32, 32), tb, 0, stream>>>(wv, Wt + 2 * 1024 * 1024, 1024, 1024);
    transpose_cvt<<<dim3(32, 2),  tb, 0, stream>>>(wo, WoT, 1024, 64);

    gemm_qkv<<<dim3(64, 24), 256, 0, stream>>>(Xb, Wt, bq, bk, bv, Qb, Kb, VTb);
    attn<<<dim3(16, 64), 256, 0, stream>>>(Qb, Kb, VTb, Ob);
    out_proj<<<512, 64, 0, stream>>>(Ob, WoT, bo, Out);
}

// Round 5
// 427.568 us; speedup vs baseline: 1.0576x; 1.0576x over previous
//
#include <hip/hip_runtime.h>

typedef __attribute__((ext_vector_type(8))) __bf16 bf16x8;
typedef __attribute__((ext_vector_type(4))) float f32x4;

#define NB   4
#define NS   2048
#define NDIN 1024
#define NH   16
#define ND   64
#define NHD  1024
#define NM   (NB * NS)  // 8192

__device__ __forceinline__ float bf2f(unsigned short u) {
    unsigned int x = ((unsigned int)u) << 16;
    return __builtin_bit_cast(float, x);
}
__device__ __forceinline__ unsigned short f2bf(float f) {
    unsigned int u = __builtin_bit_cast(unsigned int, f);
    u += 0x7fff + ((u >> 16) & 1);  // RNE
    return (unsigned short)(u >> 16);
}
// round-half-up bf16 pair pack: 2 adds + 1 v_perm
__device__ __forceinline__ unsigned int pack2bf_rhu(float a, float b) {
    unsigned int ua = __builtin_bit_cast(unsigned int, a) + 0x8000u;
    unsigned int ub = __builtin_bit_cast(unsigned int, b) + 0x8000u;
    return __builtin_amdgcn_perm(ub, ua, 0x07060302u);  // {ub.hi, ua.hi}
}

// ---------------- X: fp32 -> bf16, 8 elems/thread ----------------
__global__ __launch_bounds__(256) void cvt_x(const float* __restrict__ src,
                                             unsigned short* __restrict__ dst) {
    int i = blockIdx.x * 256 + threadIdx.x;
    float4 a = ((const float4*)src)[i * 2];
    float4 b = ((const float4*)src)[i * 2 + 1];
    union { uint4 u; unsigned short s[8]; } o;
    o.s[0] = f2bf(a.x); o.s[1] = f2bf(a.y); o.s[2] = f2bf(a.z); o.s[3] = f2bf(a.w);
    o.s[4] = f2bf(b.x); o.s[5] = f2bf(b.y); o.s[6] = f2bf(b.z); o.s[7] = f2bf(b.w);
    *(uint4*)(dst + (size_t)i * 8) = o.u;
}

// ------------- weight transpose+convert: fp32 src[K][N] -> bf16 dst[N][K] -------------
__global__ void transpose_cvt(const float* __restrict__ src,
                              unsigned short* __restrict__ dst, int K, int N) {
    __shared__ unsigned short t[32][33];
    int k0 = blockIdx.x * 32, n0 = blockIdx.y * 32;
    int tx = threadIdx.x, ty = threadIdx.y;  // block (32,8)
#pragma unroll
    for (int i = 0; i < 32; i += 8)
        t[ty + i][tx] = f2bf(src[(size_t)(k0 + ty + i) * N + (n0 + tx)]);
    __syncthreads();
#pragma unroll
    for (int i = 0; i < 32; i += 8)
        dst[(size_t)(n0 + ty + i) * K + (k0 + tx)] = t[tx][ty + i];
}

// ---------------- fused QKV projection: Xb[8192][1024] @ {wq,wk,wv} ----------------
// Q,K scattered as [B,H,S,D]; V scattered TRANSPOSED as VT[B,H,D,S].
__global__ __launch_bounds__(256) void gemm_qkv(
    const unsigned short* __restrict__ X, const unsigned short* __restrict__ Wt,
    const float* __restrict__ bq, const float* __restrict__ bk,
    const float* __restrict__ bv,
    unsigned short* __restrict__ Q, unsigned short* __restrict__ K,
    unsigned short* __restrict__ VT) {
    __shared__ unsigned short Al[128][40];
    __shared__ unsigned short Bl[128][40];
    int mb = blockIdx.x * 128;
    int nb = blockIdx.y * 128;
    int tid = threadIdx.x;
    int wid = tid >> 6, lane = tid & 63, quad = lane >> 4, l16 = lane & 15;
    int wm = (wid & 1) * 64, wn = (wid >> 1) * 64;

    f32x4 acc[4][4];
#pragma unroll
    for (int i = 0; i < 4; i++)
#pragma unroll
        for (int j = 0; j < 4; j++) acc[i][j] = (f32x4){0.f, 0.f, 0.f, 0.f};

    for (int k0 = 0; k0 < NDIN; k0 += 32) {
#pragma unroll
        for (int i = 0; i < 2; i++) {
            int c = tid + 256 * i;
            int row = c >> 2, col = (c & 3) * 8;
            uint4 a = *(const uint4*)(X + (size_t)(mb + row) * NDIN + k0 + col);
            *(uint4*)(&Al[row][col]) = a;
            uint4 b = *(const uint4*)(Wt + (size_t)(nb + row) * NDIN + k0 + col);
            *(uint4*)(&Bl[row][col]) = b;
        }
        __syncthreads();
        bf16x8 af[4], bfr[4];
#pragma unroll
        for (int i = 0; i < 4; i++)
            af[i] = *(const bf16x8*)(&Al[wm + i * 16 + l16][quad * 8]);
#pragma unroll
        for (int j = 0; j < 4; j++)
            bfr[j] = *(const bf16x8*)(&Bl[wn + j * 16 + l16][quad * 8]);
#pragma unroll
        for (int i = 0; i < 4; i++)
#pragma unroll
            for (int j = 0; j < 4; j++)
                acc[i][j] = __builtin_amdgcn_mfma_f32_16x16x32_bf16(af[i], bfr[j], acc[i][j], 0, 0, 0);
        __syncthreads();
    }

#pragma unroll
    for (int i = 0; i < 4; i++) {
#pragma unroll
        for (int j = 0; j < 4; j++) {
            int n = nb + wn + j * 16 + l16;
            int wsel = n >> 10;
            int cc = n & 1023;
            const float* bias = (wsel == 0) ? bq : (wsel == 1) ? bk : bv;
            float bias_v = bias[cc];
            int h = cc >> 6, d = cc & 63;
#pragma unroll
            for (int r = 0; r < 4; r++) {
                int m = mb + wm + i * 16 + quad * 4 + r;
                int b = m >> 11, s = m & 2047;
                unsigned short val = f2bf(acc[i][j][r] + bias_v);
                if (wsel == 0)
                    Q[((size_t)((b * NH + h) * NS + s)) * ND + d] = val;
                else if (wsel == 1)
                    K[((size_t)((b * NH + h) * NS + s)) * ND + d] = val;
                else
                    VT[((size_t)((b * NH + h) * ND + d)) * NS + s] = val;
            }
        }
    }
}

// ---------------- barrier-free transposed flash attention, K-prefetch ----------------
// S^T = K Q^T (A=K, B=Q); O^T = V^T P^T (A=V^T, B=P^T). Lane l16 owns q-column.
// Pl wave-private (no __syncthreads). K fragments ping-pong prefetched 1 chunk ahead.
__global__ __launch_bounds__(256) void attn(
    const unsigned short* __restrict__ Q, const unsigned short* __restrict__ K,
    const unsigned short* __restrict__ VT, unsigned short* __restrict__ Obuf) {
    __shared__ unsigned short Pl[4][32][72];  // per-wave P^T scratch [q][key]
    int qt = blockIdx.x;  // 0..15
    int bh = blockIdx.y;  // 0..63
    size_t kbase = (size_t)bh * NS * ND;  // K : [bh][s][d]
    size_t vbase = (size_t)bh * ND * NS;  // VT: [bh][d][s]
    int tid = threadIdx.x, wid = tid >> 6, lane = tid & 63;
    int quad = lane >> 4, l16 = lane & 15;
    int q0 = qt * 128 + wid * 32;
    const float SC = 0.18033688f;  // log2(e) / sqrt(64)

    // Q as B-operand fragments (lane=q-row, k=d); scale folded into SC
    bf16x8 qa[2][2];
#pragma unroll
    for (int s = 0; s < 2; s++)
#pragma unroll
        for (int h = 0; h < 2; h++)
            qa[s][h] = *(const bf16x8*)(Q + kbase + (size_t)(q0 + s * 16 + l16) * ND + h * 32 + quad * 8);

    bf16x8 ones;
    {
        union { uint4 u; unsigned short sv[8]; } t;
#pragma unroll
        for (int j = 0; j < 8; j++) t.sv[j] = 0x3F80;  // bf16 1.0
        ones = __builtin_bit_cast(bf16x8, t.u);
    }

    float mrow[2] = {-3e38f, -3e38f};
    f32x4 lacc[2];
    f32x4 o[2][4];
#pragma unroll
    for (int s = 0; s < 2; s++) lacc[s] = (f32x4){0.f, 0.f, 0.f, 0.f};
#pragma unroll
    for (int s = 0; s < 2; s++)
#pragma unroll
        for (int t = 0; t < 4; t++) o[s][t] = (f32x4){0.f, 0.f, 0.f, 0.f};

    auto loadK = [&](int kc, bf16x8 (&kb)[4][2]) {
#pragma unroll
        for (int sub = 0; sub < 4; sub++)
#pragma unroll
            for (int h = 0; h < 2; h++)
                kb[sub][h] = *(const bf16x8*)(K + kbase + (size_t)(kc + sub * 16 + l16) * ND + h * 32 + quad * 8);
    };

    auto process = [&](const bf16x8 (&kb)[4][2], int kc) {
        // S^T tiles: C[m=key][n=q]
        f32x4 sc[2][4];
#pragma unroll
        for (int sub = 0; sub < 4; sub++)
#pragma unroll
            for (int s = 0; s < 2; s++) {
                f32x4 c = (f32x4){0.f, 0.f, 0.f, 0.f};
                c = __builtin_amdgcn_mfma_f32_16x16x32_bf16(kb[sub][0], qa[s][0], c, 0, 0, 0);
                c = __builtin_amdgcn_mfma_f32_16x16x32_bf16(kb[sub][1], qa[s][1], c, 0, 0, 0);
                sc[s][sub] = c;
            }

        // V^T A-fragments: issue now, consumed after softmax (latency hidden)
        bf16x8 vb[4][2];
#pragma unroll
        for (int t = 0; t < 4; t++)
#pragma unroll
            for (int h = 0; h < 2; h++)
                vb[t][h] = *(const bf16x8*)(VT + vbase + (size_t)(t * 16 + l16) * NS + kc + h * 32 + quad * 8);

        // online softmax: lane owns q-column l16 -> one (m,l) per s
#pragma unroll
        for (int s = 0; s < 2; s++) {
            float mx = sc[s][0][0];
#pragma unroll
            for (int sub = 0; sub < 4; sub++)
#pragma unroll
                for (int r = 0; r < 4; r++) mx = fmaxf(mx, sc[s][sub][r]);
            mx = fmaxf(mx, __shfl_xor(mx, 16, 64));
            mx = fmaxf(mx, __shfl_xor(mx, 32, 64));
            float mn = fmaxf(mrow[s], mx);
            float alpha = __builtin_exp2f((mrow[s] - mn) * SC);
            mrow[s] = mn;
            float mc = mn * SC;
#pragma unroll
            for (int t = 0; t < 4; t++) o[s][t] *= alpha;
            lacc[s] *= alpha;
#pragma unroll
            for (int sub = 0; sub < 4; sub++) {
                float p0 = __builtin_exp2f(fmaf(sc[s][sub][0], SC, -mc));
                float p1 = __builtin_exp2f(fmaf(sc[s][sub][1], SC, -mc));
                float p2 = __builtin_exp2f(fmaf(sc[s][sub][2], SC, -mc));
                float p3 = __builtin_exp2f(fmaf(sc[s][sub][3], SC, -mc));
                uint2 pk;
                pk.x = pack2bf_rhu(p0, p1);
                pk.y = pack2bf_rhu(p2, p3);
                *(uint2*)(&Pl[wid][s * 16 + l16][sub * 16 + quad * 4]) = pk;
            }
        }

        // same-wave DS ordering; compiler inserts minimal lgkmcnt before use
#pragma unroll
        for (int s = 0; s < 2; s++) {
            bf16x8 pb0 = *(const bf16x8*)(&Pl[wid][s * 16 + l16][quad * 8]);
            bf16x8 pb1 = *(const bf16x8*)(&Pl[wid][s * 16 + l16][32 + quad * 8]);
#pragma unroll
            for (int t = 0; t < 4; t++) {
                o[s][t] = __builtin_amdgcn_mfma_f32_16x16x32_bf16(vb[t][0], pb0, o[s][t], 0, 0, 0);
                o[s][t] = __builtin_amdgcn_mfma_f32_16x16x32_bf16(vb[t][1], pb1, o[s][t], 0, 0, 0);
            }
            lacc[s] = __builtin_amdgcn_mfma_f32_16x16x32_bf16(ones, pb0, lacc[s], 0, 0, 0);
            lacc[s] = __builtin_amdgcn_mfma_f32_16x16x32_bf16(ones, pb1, lacc[s], 0, 0, 0);
        }
    };

    bf16x8 kbA[4][2], kbB[4][2];
    loadK(0, kbA);
    for (int i = 0; i < NS / 128; i++) {
        int kc = i * 128;
        loadK(kc + 64, kbB);                 // prefetch: ~1 chunk of overlap
        process(kbA, kc);
        loadK((kc + 128) & (NS - 1), kbA);   // wraps harmlessly on last iter
        process(kbB, kc + 64);
    }

    // epilogue: O^T C-layout -> Obuf[m][h*64+d], packed pair stores
    int b = bh >> 4, h = bh & 15;
#pragma unroll
    for (int s = 0; s < 2; s++) {
        float rl = 1.0f / lacc[s][0];
        size_t row = (size_t)(b * NS + q0 + s * 16 + l16) * NHD + h * ND;
#pragma unroll
        for (int t = 0; t < 4; t++) {
            int d = t * 16 + quad * 4;
            *(unsigned int*)(&Obuf[row + d])     = pack2bf_rhu(o[s][t][0] * rl, o[s][t][1] * rl);
            *(unsigned int*)(&Obuf[row + d + 2]) = pack2bf_rhu(o[s][t][2] * rl, o[s][t][3] * rl);
        }
    }
}

// ---------------- output projection: Obuf[8192][1024] @ wo[1024][64] + bo -> fp32 ----------------
__global__ __launch_bounds__(64) void out_proj(
    const unsigned short* __restrict__ Obuf, const unsigned short* __restrict__ WoT,
    const float* __restrict__ bo, float* __restrict__ Out) {
    int m0 = blockIdx.x * 16;
    int lane = threadIdx.x, quad = lane >> 4, l16 = lane & 15;
    f32x4 acc[4];
#pragma unroll
    for (int t = 0; t < 4; t++) acc[t] = (f32x4){0.f, 0.f, 0.f, 0.f};
    for (int k0 = 0; k0 < NHD; k0 += 32) {
        bf16x8 a = *(const bf16x8*)(Obuf + (size_t)(m0 + l16) * NHD + k0 + quad * 8);
#pragma unroll
        for (int t = 0; t < 4; t++) {
            bf16x8 b = *(const bf16x8*)(WoT + (size_t)(t * 16 + l16) * NHD + k0 + quad * 8);
            acc[t] = __builtin_amdgcn_mfma_f32_16x16x32_bf16(a, b, acc[t], 0, 0, 0);
        }
    }
#pragma unroll
    for (int t = 0; t < 4; t++) {
        int n = t * 16 + l16;
        float bb = bo[n];
#pragma unroll
        for (int r = 0; r < 4; r++) {
            int m = m0 + quad * 4 + r;
            Out[(size_t)m * ND + n] = acc[t][r] + bb;
        }
    }
}

extern "C" void kernel_launch(void* const* d_in, const int* in_sizes, int n_in,
                              void* d_out, int out_size, void* d_ws, size_t ws_size,
                              hipStream_t stream) {
    const float* X  = (const float*)d_in[0];
    const float* wq = (const float*)d_in[1];
    const float* bq = (const float*)d_in[2];
    const float* wk = (const float*)d_in[3];
    const float* bk = (const float*)d_in[4];
    const float* wv = (const float*)d_in[5];
    const float* bv = (const float*)d_in[6];
    const float* wo = (const float*)d_in[7];
    const float* bo = (const float*)d_in[8];
    float* Out = (float*)d_out;

    char* w = (char*)d_ws;
    unsigned short* Wt  = (unsigned short*)w; w += (size_t)3072 * 1024 * 2;
    unsigned short* WoT = (unsigned short*)w; w += (size_t)64 * 1024 * 2;
    unsigned short* Xb  = (unsigned short*)w; w += (size_t)NM * NDIN * 2;
    unsigned short* Qb  = (unsigned short*)w; w += (size_t)NM * NHD * 2;
    unsigned short* Kb  = (unsigned short*)w; w += (size_t)NM * NHD * 2;
    unsigned short* VTb = (unsigned short*)w; w += (size_t)NM * NHD * 2;
    unsigned short* Ob  = (unsigned short*)w; w += (size_t)NM * NHD * 2;

    cvt_x<<<NM * NDIN / (256 * 8), 256, 0, stream>>>(X, Xb);

    dim3 tb(32, 8);
    transpose_cvt<<<dim3(32, 32), tb, 0, stream>>>(wq, Wt, 1024, 1024);
    transpose_cvt<<<dim3(32, 32), tb, 0, stream>>>(wk, Wt + 1024 * 1024, 1024, 1024);
    transpose_cvt<<<dim3(32, 32), tb, 0, stream>>>(wv, Wt + 2 * 1024 * 1024, 1024, 1024);
    transpose_cvt<<<dim3(32, 2),  tb, 0, stream>>>(wo, WoT, 1024, 64);

    gemm_qkv<<<dim3(64, 24), 256, 0, stream>>>(Xb, Wt, bq, bk, bv, Qb, Kb, VTb);
    attn<<<dim3(16, 64), 256, 0, stream>>>(Qb, Kb, VTb, Ob);
    out_proj<<<512, 64, 0, stream>>>(Ob, WoT, bo, Out);
}